// Round 3
// baseline (139.367 us; speedup 1.0000x reference)
//
#include <hip/hip_runtime.h>
#include <type_traits>

// Inverse DTCWT (biort legall) — fused, async double-buffered LDS staging.
// Per block: one (b*C+c) plane x TH-row output tile.
// Stage s loads subband-row-pair data for stage s+1 via global_load_lds
// (width 16, LDS-linear layout) while computing stage s from the other
// buffer. One __syncthreads per stage (its vmcnt(0) drain is the only wait).

#define Hh 256
#define Ww 256
#define W2 128
#define SBsz (128 * 128)
#define TH 32
#define NST (TH / 2 + 2)   // 18 stages: pairs ip0-1 .. ip0+16 (reflected)
#define YOFF 1536          // Yl rows at float offset 1536 in each buffer

__device__ __forceinline__ int reflect_idx(int m, int N) {
    if (m < 0) m = -m - 1;
    if (m >= N) m = 2 * N - 1 - m;
    return m;
}

__device__ __forceinline__ void async_load16(const float* src, float* lds) {
    __builtin_amdgcn_global_load_lds(
        (const __attribute__((address_space(1))) void*)src,
        (__attribute__((address_space(3))) void*)lds, 16, 0, 0);
}

__global__ __launch_bounds__(256, 8) void dtcwt_inv(
    const float* __restrict__ Yl,
    const float* __restrict__ Yhr,
    const float* __restrict__ Yhi,
    const float* __restrict__ g0o,
    const float* __restrict__ g1o,
    float* __restrict__ out)
{
    const float SC = 0.70710678118654752440f;  // sqrt(0.5)
    __shared__ float buf[2][2048];  // per buffer: 12x128 subband rows + 2x256 Yl rows

    const int j = threadIdx.x;
    const int plane = blockIdx.x;
    const int i0 = blockIdx.y * TH;
    const int ip0 = i0 >> 1;

    const float* yl  = Yl  + (size_t)plane * (Hh * Ww);
    const float* phr = Yhr + (size_t)plane * 6 * SBsz;
    const float* phi = Yhi + (size_t)plane * 6 * SBsz;
    float* outp = out + (size_t)plane * (Hh * Ww);

    float g0[3], g1[5], g0s[3], g1s[5];
#pragma unroll
    for (int t = 0; t < 3; ++t) { g0[t] = g0o[t]; g0s[t] = g0[t] * SC; }
#pragma unroll
    for (int t = 0; t < 5; ++t) { g1[t] = g1o[t]; g1s[t] = g1[t] * SC; }

    const int jm1 = reflect_idx(j - 1, Ww);
    const int jp1 = reflect_idx(j + 1, Ww);
    int soff0[5], soff1[5];  // LDS col offset (+768 selects imag block)
    float sg[5];             // sign for odd-row parity
#pragma unroll
    for (int t = 0; t < 5; ++t) {
        int jj = reflect_idx(j - 2 + t, Ww);
        int jc = jj >> 1, v = jj & 1;
        soff0[t] = jc + (v ? 768 : 0);
        soff1[t] = jc + (v ? 0 : 768);
        sg[t] = v ? -1.f : 1.f;
    }

    // Issue async loads for stage s into buf[s&1]. 512 float4 per stage:
    // f<384: subband rows (q = f>>5, 12 rows x 32 float4); f>=384: 2 Yl rows.
    auto issue = [&](int s) {
        int v = ip0 - 1 + s;
        int ip = v < 0 ? 0 : (v > 127 ? 127 : v);
        float* B = buf[s & 1];
#pragma unroll
        for (int rep = 0; rep < 2; ++rep) {
            int f = j + rep * 256;
            const float* src;
            if (f < 384) {
                int q = f >> 5;
                int col = (f & 31) << 2;
                const float* bq = (q < 6) ? (phr + (size_t)q * SBsz)
                                          : (phi + (size_t)(q - 6) * SBsz);
                src = bq + ip * W2 + col;
            } else {
                int g = f - 384;
                src = yl + (size_t)(2 * ip + (g >> 6)) * Ww + ((g & 63) << 2);
            }
            async_load16(src, B + 4 * f);
        }
    };

    // y1,y2 at row parity u of the staged pair (u compile-time).
    auto compute = [&](const float* B, auto UC, float& o1, float& o2) {
        constexpr int u = decltype(UC)::value;
        float y1 = g0[0] * B[YOFF + u * 256 + jm1]
                 + g0[1] * B[YOFF + u * 256 + j]
                 + g0[2] * B[YOFF + u * 256 + jp1];
        float y2 = 0.f;
#pragma unroll
        for (int t = 0; t < 5; ++t) {
            const int so = u ? soff1[t] : soff0[t];
            const float cc = u ? g1s[t] * sg[t] : g1s[t];
            float s1 = B[256 + so], s2 = B[384 + so];   // hl pair (2,3)
            y1 += cc * (u ? s1 - s2 : s1 + s2);
            float e1 = B[128 + so], e2 = B[512 + so];   // hh pair (1,4)
            y2 += cc * (u ? e1 - e2 : e1 + e2);
            if (t >= 1 && t <= 3) {
                const float c0 = u ? g0s[t - 1] * sg[t] : g0s[t - 1];
                float l1 = B[so], l2 = B[640 + so];     // lh pair (0,5)
                y2 += c0 * (u ? l1 - l2 : l1 + l2);
            }
        }
        o1 = y1; o2 = y2;
    };
    std::integral_constant<int, 0> U0;
    std::integral_constant<int, 1> U1;

    issue(0);

    float h1[4], h2[4];  // y1,y2 at rows r0-2..r0+1
    for (int s = 0; s < NST; ++s) {
        __syncthreads();               // drains vmcnt(0) then barriers
        if (s + 1 < NST) issue(s + 1); // overlap next stage's loads w/ compute
        const float* B = buf[s & 1];
        float c1, c2, d1, d2;
        compute(B, U0, c1, c2);        // physical even row
        compute(B, U1, d1, d2);        // physical odd row
        int v = ip0 - 1 + s;
        bool rev = (v < 0) || (v > 127);  // top/bottom reflection swaps order
        float a1 = rev ? d1 : c1, a2 = rev ? d2 : c2;
        float b1 = rev ? c1 : d1, b2 = rev ? c2 : d2;
        if (s == 0)      { h1[0] = a1; h1[1] = b1; h2[0] = a2; h2[1] = b2; }
        else if (s == 1) { h1[2] = a1; h1[3] = b1; h2[2] = a2; h2[3] = b2; }
        else {
            const int r0 = i0 + 2 * (s - 2);
            float o0 = g0[0] * h1[1] + g0[1] * h1[2] + g0[2] * h1[3]
                     + g1[0] * h2[0] + g1[1] * h2[1] + g1[2] * h2[2]
                     + g1[3] * h2[3] + g1[4] * a2;
            float o1v = g0[0] * h1[2] + g0[1] * h1[3] + g0[2] * a1
                      + g1[0] * h2[1] + g1[1] * h2[2] + g1[2] * h2[3]
                      + g1[3] * a2 + g1[4] * b2;
            outp[(size_t)r0 * Ww + j] = o0;
            outp[(size_t)(r0 + 1) * Ww + j] = o1v;
            h1[0] = h1[2]; h1[1] = h1[3]; h1[2] = a1; h1[3] = b1;
            h2[0] = h2[2]; h2[1] = h2[3]; h2[2] = a2; h2[3] = b2;
        }
    }
}

extern "C" void kernel_launch(void* const* d_in, const int* in_sizes, int n_in,
                              void* d_out, int out_size, void* d_ws, size_t ws_size,
                              hipStream_t stream) {
    const float* Yl  = (const float*)d_in[0];
    const float* Yhr = (const float*)d_in[1];
    const float* Yhi = (const float*)d_in[2];
    const float* g0o = (const float*)d_in[3];
    const float* g1o = (const float*)d_in[4];
    float* outp = (float*)d_out;
    dim3 grid(256, Hh / TH);  // 256 planes x 8 row tiles
    dim3 block(256);
    hipLaunchKernelGGL(dtcwt_inv, grid, block, 0, stream,
                       Yl, Yhr, Yhi, g0o, g1o, outp);
}

// Round 4
// 73.914 us; speedup vs baseline: 1.8855x; 1.8855x over previous
//
#include <hip/hip_runtime.h>

// Inverse DTCWT (biort legall) — fused, 2 output cols/thread, reg-reuse of
// subband LDS reads across both row parities, double-buffered LDS with
// reg-staged float4 loads and raw s_barrier (no vmcnt(0) drain).

#define Hh 256
#define Ww 256
#define W2 128
#define SBsz (128 * 128)
#define TH 32
#define NST (TH / 2 + 2)     // 18 stages: row-pairs ip0-1 .. ip0+16 (reflected)
#define YLSTR 288            // skewed Yl row stride (max addr 255+28=283)
#define YOFF 1536
#define BUFSZ (YOFF + 2 * YLSTR)   // 2112 floats per buffer

__device__ __forceinline__ int reflect_idx(int m, int N) {
    if (m < 0) m = -m - 1;
    if (m >= N) m = 2 * N - 1 - m;
    return m;
}
// skew: spread stride-2 column accesses across banks (col + 4*(col/32))
__device__ __forceinline__ int skew(int col) { return col + ((col >> 5) << 2); }

__global__ __launch_bounds__(128, 4) void dtcwt_inv(
    const float* __restrict__ Yl,
    const float* __restrict__ Yhr,
    const float* __restrict__ Yhi,
    const float* __restrict__ g0o,
    const float* __restrict__ g1o,
    float* __restrict__ out)
{
    const float SC = 0.70710678118654752440f;  // sqrt(0.5)
    __shared__ float buf[2][BUFSZ];

    const int c = threadIdx.x;         // subband col; output cols 2c, 2c+1
    const int plane = blockIdx.x;
    const int i0 = blockIdx.y * TH;
    const int ip0 = i0 >> 1;

    const float* yl  = Yl  + (size_t)plane * (Hh * Ww);
    const float* phr = Yhr + (size_t)plane * 6 * SBsz;
    const float* phi = Yhi + (size_t)plane * 6 * SBsz;
    float* outp = out + (size_t)plane * (Hh * Ww);

    float g0[3], g1[5], g0s[3], g1s[5];
#pragma unroll
    for (int t = 0; t < 3; ++t) { g0[t] = g0o[t]; g0s[t] = g0[t] * SC; }
#pragma unroll
    for (int t = 0; t < 5; ++t) { g1[t] = g1o[t]; g1s[t] = g1[t] * SC; }

    // Quad-col tables: qcols 2c-2 .. 2c+3 -> slot (k>>1) col + parity.
    int jcs[3], vq[6];
#pragma unroll
    for (int k = 0; k < 6; ++k) {
        int qq = reflect_idx(2 * c - 2 + k, Ww);
        if ((k & 1) == 0) jcs[k >> 1] = qq >> 1;
        vq[k] = qq & 1;
    }
    const int ylc0 = skew(reflect_idx(2 * c - 1, Ww));
    const int ylc1 = skew(2 * c);
    const int ylc2 = skew(2 * c + 1);
    const int ylc3 = skew(reflect_idx(2 * c + 2, Ww));

    // Staging: 512 float4/stage, 4 per thread (3 subband + 1 Yl).
    const int col4 = (c & 31) << 2;
    const float* bp0; const float* bp1; const float* bp2;
    {
        int q0 = (c >> 5), q1 = 4 + (c >> 5), q2 = 8 + (c >> 5);
        bp0 = ((q0 < 6) ? phr + (size_t)q0 * SBsz : phi + (size_t)(q0 - 6) * SBsz) + col4;
        bp1 = ((q1 < 6) ? phr + (size_t)q1 * SBsz : phi + (size_t)(q1 - 6) * SBsz) + col4;
        bp2 = ((q2 < 6) ? phr + (size_t)q2 * SBsz : phi + (size_t)(q2 - 6) * SBsz) + col4;
    }
    const int yrow = c >> 6;
    const int ycol = (c & 63) << 2;
    const int ydst = YOFF + yrow * YLSTR + skew(ycol);
    const int sdst = 4 * c;

    float4 pf0, pf1, pf2, pfY;
    auto loadregs = [&](int s) {
        int v = ip0 - 1 + s;
        int ip = v < 0 ? 0 : (v > 127 ? 127 : v);
        pf0 = *(const float4*)(bp0 + ip * W2);
        pf1 = *(const float4*)(bp1 + ip * W2);
        pf2 = *(const float4*)(bp2 + ip * W2);
        pfY = *(const float4*)(yl + (size_t)(2 * ip + yrow) * Ww + ycol);
    };
    auto writeregs = [&](int s) {
        float* B = buf[s & 1];
        *(float4*)(B + sdst)        = pf0;
        *(float4*)(B + 512 + sdst)  = pf1;
        *(float4*)(B + 1024 + sdst) = pf2;
        *(float4*)(B + ydst)        = pfY;
    };

    float w1a[4], w1b[4], w2a[4], w2b[4];  // column windows, δ=0 (a) / δ=1 (b)

    loadregs(0);
    writeregs(0);
    loadregs(1);
    asm volatile("s_waitcnt lgkmcnt(0)" ::: "memory");
    __builtin_amdgcn_s_barrier();

    for (int s = 0; s < NST; ++s) {
        const float* B = buf[s & 1];
        // ---- compute: 8 y-values (y1,y2 at 2 parities x 2 cols) ----
        float ya0 = B[YOFF + ylc0], ya1 = B[YOFF + ylc1];
        float ya2 = B[YOFF + ylc2], ya3 = B[YOFF + ylc3];
        float yb0 = B[YOFF + YLSTR + ylc0], yb1 = B[YOFF + YLSTR + ylc1];
        float yb2 = B[YOFF + YLSTR + ylc2], yb3 = B[YOFF + YLSTR + ylc3];
        float y1_00 = g0[0] * ya0 + g0[1] * ya1 + g0[2] * ya2;
        float y1_01 = g0[0] * ya1 + g0[1] * ya2 + g0[2] * ya3;
        float y1_10 = g0[0] * yb0 + g0[1] * yb1 + g0[2] * yb2;
        float y1_11 = g0[0] * yb1 + g0[1] * yb2 + g0[2] * yb3;
        float y2_00 = 0.f, y2_01 = 0.f, y2_10 = 0.f, y2_11 = 0.f;
#pragma unroll
        for (int m = 0; m < 3; ++m) {
            const int col = jcs[m];
            float lr1 = B[col],           lr2 = B[640 + col];        // lh: bands 0,5
            float hr1 = B[256 + col],     hr2 = B[384 + col];        // hl: bands 2,3
            float er1 = B[128 + col],     er2 = B[512 + col];        // hh: bands 1,4
            float li1 = B[768 + col],       li2 = B[768 + 640 + col];
            float hi1 = B[768 + 256 + col], hi2 = B[768 + 384 + col];
            float ei1 = B[768 + 128 + col], ei2 = B[768 + 512 + col];
            float lSr = lr1 + lr2, lSi = li1 + li2, lDi = li1 - li2, lDr = lr2 - lr1;
            float hSr = hr1 + hr2, hSi = hi1 + hi2, hDi = hi1 - hi2, hDr = hr2 - hr1;
            float eSr = er1 + er2, eSi = ei1 + ei2, eDi = ei1 - ei2, eDr = er2 - er1;
#pragma unroll
            for (int kk = 0; kk < 2; ++kk) {
                const int k = 2 * m + kk;
                const int vv = vq[k];
                float qh0 = vv ? hSi : hSr, qh1 = vv ? hDr : hDi;
                float qe0 = vv ? eSi : eSr, qe1 = vv ? eDr : eDi;
                float ql0 = vv ? lSi : lSr, ql1 = vv ? lDr : lDi;
                if (k <= 4) {
                    y1_00 += g1s[k] * qh0; y1_10 += g1s[k] * qh1;
                    y2_00 += g1s[k] * qe0; y2_10 += g1s[k] * qe1;
                }
                if (k >= 1) {
                    y1_01 += g1s[k - 1] * qh0; y1_11 += g1s[k - 1] * qh1;
                    y2_01 += g1s[k - 1] * qe0; y2_11 += g1s[k - 1] * qe1;
                }
                if (k >= 1 && k <= 3) {
                    y2_00 += g0s[k - 1] * ql0; y2_10 += g0s[k - 1] * ql1;
                }
                if (k >= 2 && k <= 4) {
                    y2_01 += g0s[k - 2] * ql0; y2_11 += g0s[k - 2] * ql1;
                }
            }
        }
        // ---- reflection order + column sliding window ----
        int v = ip0 - 1 + s;
        bool rev = (v < 0) || (v > 127);
        float a1A = rev ? y1_10 : y1_00, a2A = rev ? y2_10 : y2_00;
        float b1A = rev ? y1_00 : y1_10, b2A = rev ? y2_00 : y2_10;
        float a1B = rev ? y1_11 : y1_01, a2B = rev ? y2_11 : y2_01;
        float b1B = rev ? y1_01 : y1_11, b2B = rev ? y2_01 : y2_11;
        if (s == 0) {
            w1a[0] = a1A; w1a[1] = b1A; w2a[0] = a2A; w2a[1] = b2A;
            w1b[0] = a1B; w1b[1] = b1B; w2b[0] = a2B; w2b[1] = b2B;
        } else if (s == 1) {
            w1a[2] = a1A; w1a[3] = b1A; w2a[2] = a2A; w2a[3] = b2A;
            w1b[2] = a1B; w1b[3] = b1B; w2b[2] = a2B; w2b[3] = b2B;
        } else {
            const int r0 = i0 + 2 * (s - 2);
            float o0A = g0[0] * w1a[1] + g0[1] * w1a[2] + g0[2] * w1a[3]
                      + g1[0] * w2a[0] + g1[1] * w2a[1] + g1[2] * w2a[2]
                      + g1[3] * w2a[3] + g1[4] * a2A;
            float o1A = g0[0] * w1a[2] + g0[1] * w1a[3] + g0[2] * a1A
                      + g1[0] * w2a[1] + g1[1] * w2a[2] + g1[2] * w2a[3]
                      + g1[3] * a2A + g1[4] * b2A;
            float o0B = g0[0] * w1b[1] + g0[1] * w1b[2] + g0[2] * w1b[3]
                      + g1[0] * w2b[0] + g1[1] * w2b[1] + g1[2] * w2b[2]
                      + g1[3] * w2b[3] + g1[4] * a2B;
            float o1B = g0[0] * w1b[2] + g0[1] * w1b[3] + g0[2] * a1B
                      + g1[0] * w2b[1] + g1[1] * w2b[2] + g1[2] * w2b[3]
                      + g1[3] * a2B + g1[4] * b2B;
            ((float2*)outp)[r0 * 128 + c] = make_float2(o0A, o0B);
            ((float2*)outp)[(r0 + 1) * 128 + c] = make_float2(o1A, o1B);
            w1a[0] = w1a[2]; w1a[1] = w1a[3]; w1a[2] = a1A; w1a[3] = b1A;
            w2a[0] = w2a[2]; w2a[1] = w2a[3]; w2a[2] = a2A; w2a[3] = b2A;
            w1b[0] = w1b[2]; w1b[1] = w1b[3]; w1b[2] = a1B; w1b[3] = b1B;
            w2b[0] = w2b[2]; w2b[1] = w2b[3]; w2b[2] = a2B; w2b[3] = b2B;
        }
        // ---- stage s+1 write (regs prefetched last iter), s+2 load issue ----
        if (s + 1 < NST) writeregs(s + 1);
        if (s + 2 < NST) loadregs(s + 2);
        asm volatile("s_waitcnt lgkmcnt(0)" ::: "memory");
        __builtin_amdgcn_s_barrier();
    }
}

extern "C" void kernel_launch(void* const* d_in, const int* in_sizes, int n_in,
                              void* d_out, int out_size, void* d_ws, size_t ws_size,
                              hipStream_t stream) {
    const float* Yl  = (const float*)d_in[0];
    const float* Yhr = (const float*)d_in[1];
    const float* Yhi = (const float*)d_in[2];
    const float* g0o = (const float*)d_in[3];
    const float* g1o = (const float*)d_in[4];
    float* outp = (float*)d_out;
    dim3 grid(256, Hh / TH);  // 256 planes x 8 row tiles
    dim3 block(128);
    hipLaunchKernelGGL(dtcwt_inv, grid, block, 0, stream,
                       Yl, Yhr, Yhi, g0o, g1o, outp);
}

// Round 5
// 72.006 us; speedup vs baseline: 1.9355x; 1.0265x over previous
//
#include <hip/hip_runtime.h>

// Inverse DTCWT (biort legall) — quad-expanded LDS, single-wave blocks.
// Staging performs c2q (sum/diff combos, sqrt(0.5) folded, edges reflected)
// and writes 6 quad rows + 2 Yl rows per subband-row-pair into LDS.
// Compute is pure FMA on lane-contiguous b64/b128 LDS reads: 4 output cols
// per thread, 64 threads = 256 cols, one wave per block (no barriers),
// double-buffered LDS + A/B register staging with 2-stage load-ahead.

#define Hh 256
#define Ww 256
#define W2 128
#define SBsz (128 * 128)
#define TH 32
#define NST (TH / 2 + 2)   // 18 stages: row-pairs ip0-1 .. ip0+16 (reflected)
#define QSTR 264           // floats per LDS row (cols at [4+col], edges [2..3],[260..261])
#define BUFF (8 * QSTR)    // 6 quad rows + 2 Yl rows = 2112 floats

struct V8 { float x[8]; };

__device__ __forceinline__ V8 readrow(const float* B, int rho, int c) {
    const float* R = B + rho * QSTR + 4 * c + 2;
    float2 a = *(const float2*)R;
    float4 m = *(const float4*)(R + 2);
    float2 z = *(const float2*)(R + 6);
    V8 r;
    r.x[0] = a.x; r.x[1] = a.y; r.x[2] = m.x; r.x[3] = m.y;
    r.x[4] = m.z; r.x[5] = m.w; r.x[6] = z.x; r.x[7] = z.y;
    return r;
}

struct Stage {
    float s1r[6], s2r[6], s1i[6], s2i[6];  // 6 tasks: (pair p, col half k)
    float4 y0, y1;
};

__global__ __launch_bounds__(64) void dtcwt_inv(
    const float* __restrict__ Yl,
    const float* __restrict__ Yhr,
    const float* __restrict__ Yhi,
    const float* __restrict__ g0o,
    const float* __restrict__ g1o,
    float* __restrict__ out)
{
    const float SC = 0.70710678118654752440f;  // sqrt(0.5)
    __shared__ float buf[2][BUFF];

    const int c = threadIdx.x;            // 0..63; output cols 4c..4c+3
    const int plane = blockIdx.x;
    const int i0 = blockIdx.y * TH;
    const int ip0 = i0 >> 1;

    const float* yl  = Yl  + (size_t)plane * (Hh * Ww);
    const float* phr = Yhr + (size_t)plane * 6 * SBsz;
    const float* phi = Yhi + (size_t)plane * 6 * SBsz;
    float* outp = out + (size_t)plane * (Hh * Ww);

    float g0[3], g1[5];
#pragma unroll
    for (int t = 0; t < 3; ++t) g0[t] = g0o[t];
#pragma unroll
    for (int t = 0; t < 5; ++t) g1[t] = g1o[t];

    // pair p -> subband indices (a1, a2): lh=(0,5), hl=(2,3), hh=(1,4)
    constexpr int PB1[3] = {0, 2, 1};
    constexpr int PB2[3] = {5, 3, 4};

    Stage SA, SB;

    auto loadStage = [&](int s, Stage& S) {
        int sc_ = s < NST ? s : NST - 1;
        int v = ip0 - 1 + sc_;
        int ip = v < 0 ? 0 : (v > 127 ? 127 : v);
        const int off = ip * W2 + c;
#pragma unroll
        for (int p = 0; p < 3; ++p) {
#pragma unroll
            for (int k = 0; k < 2; ++k) {
                const int r = 2 * p + k;
                const int o = off + 64 * k;
                S.s1r[r] = phr[PB1[p] * SBsz + o];
                S.s2r[r] = phr[PB2[p] * SBsz + o];
                S.s1i[r] = phi[PB1[p] * SBsz + o];
                S.s2i[r] = phi[PB2[p] * SBsz + o];
            }
        }
        S.y0 = *(const float4*)(yl + (size_t)(2 * ip) * Ww + 4 * c);
        S.y1 = *(const float4*)(yl + (size_t)(2 * ip + 1) * Ww + 4 * c);
    };

    auto writeStage = [&](int s, const Stage& S) {
        float* B = buf[s & 1];
#pragma unroll
        for (int p = 0; p < 3; ++p) {
#pragma unroll
            for (int k = 0; k < 2; ++k) {
                const int r = 2 * p + k;
                const int col = c + 64 * k;
                float Sr = SC * (S.s1r[r] + S.s2r[r]);
                float Si = SC * (S.s1i[r] + S.s2i[r]);
                float Di = SC * (S.s1i[r] - S.s2i[r]);
                float Dr = SC * (S.s2r[r] - S.s1r[r]);
                float* Q0 = B + (2 * p) * QSTR;      // parity u=0: [Sr,Si]
                float* Q1 = B + (2 * p + 1) * QSTR;  // parity u=1: [Di,Dr]
                *(float2*)(Q0 + 4 + 2 * col) = make_float2(Sr, Si);
                *(float2*)(Q1 + 4 + 2 * col) = make_float2(Di, Dr);
                if (k == 0 && c == 0) {    // qcols -2,-1 -> reflect 1,0
                    *(float2*)(Q0 + 2) = make_float2(Si, Sr);
                    *(float2*)(Q1 + 2) = make_float2(Dr, Di);
                }
                if (k == 1 && c == 63) {   // qcols 256,257 -> reflect 255,254
                    *(float2*)(Q0 + 260) = make_float2(Si, Sr);
                    *(float2*)(Q1 + 260) = make_float2(Dr, Di);
                }
            }
        }
        float* Y0 = B + 6 * QSTR;
        float* Y1 = B + 7 * QSTR;
        *(float4*)(Y0 + 4 + 4 * c) = S.y0;
        *(float4*)(Y1 + 4 + 4 * c) = S.y1;
        if (c == 0)  { Y0[3] = S.y0.x;   Y1[3] = S.y1.x; }    // col -1 -> col 0
        if (c == 63) { Y0[260] = S.y0.w; Y1[260] = S.y1.w; }  // col 256 -> 255
    };

    float w1[4][4], w2[4][4];  // per-col column-filter windows

    auto compute = [&](int s) {
        const float* B = buf[s & 1];
        V8 L0 = readrow(B, 0, c), L1 = readrow(B, 1, c);   // lh quad u0,u1
        V8 H0 = readrow(B, 2, c), H1 = readrow(B, 3, c);   // hl quad
        V8 E0 = readrow(B, 4, c), E1 = readrow(B, 5, c);   // hh quad
        V8 Ya = readrow(B, 6, c), Yb = readrow(B, 7, c);   // Yl rows
        float y10[4], y11[4], y20[4], y21[4];
#pragma unroll
        for (int dx = 0; dx < 4; ++dx) {
            y10[dx] = g0[0]*Ya.x[dx+1] + g0[1]*Ya.x[dx+2] + g0[2]*Ya.x[dx+3]
                    + g1[0]*H0.x[dx]   + g1[1]*H0.x[dx+1] + g1[2]*H0.x[dx+2]
                    + g1[3]*H0.x[dx+3] + g1[4]*H0.x[dx+4];
            y11[dx] = g0[0]*Yb.x[dx+1] + g0[1]*Yb.x[dx+2] + g0[2]*Yb.x[dx+3]
                    + g1[0]*H1.x[dx]   + g1[1]*H1.x[dx+1] + g1[2]*H1.x[dx+2]
                    + g1[3]*H1.x[dx+3] + g1[4]*H1.x[dx+4];
            y20[dx] = g0[0]*L0.x[dx+1] + g0[1]*L0.x[dx+2] + g0[2]*L0.x[dx+3]
                    + g1[0]*E0.x[dx]   + g1[1]*E0.x[dx+1] + g1[2]*E0.x[dx+2]
                    + g1[3]*E0.x[dx+3] + g1[4]*E0.x[dx+4];
            y21[dx] = g0[0]*L1.x[dx+1] + g0[1]*L1.x[dx+2] + g0[2]*L1.x[dx+3]
                    + g1[0]*E1.x[dx]   + g1[1]*E1.x[dx+1] + g1[2]*E1.x[dx+2]
                    + g1[3]*E1.x[dx+3] + g1[4]*E1.x[dx+4];
        }
        int v = ip0 - 1 + s;
        bool rev = (v < 0) || (v > 127);  // edge reflection swaps row order
        float o0[4], o1[4];
#pragma unroll
        for (int dx = 0; dx < 4; ++dx) {
            float A1 = rev ? y11[dx] : y10[dx];
            float Bb1 = rev ? y10[dx] : y11[dx];
            float A2 = rev ? y21[dx] : y20[dx];
            float Bb2 = rev ? y20[dx] : y21[dx];
            if (s == 0) {
                w1[dx][0] = A1; w1[dx][1] = Bb1; w2[dx][0] = A2; w2[dx][1] = Bb2;
            } else if (s == 1) {
                w1[dx][2] = A1; w1[dx][3] = Bb1; w2[dx][2] = A2; w2[dx][3] = Bb2;
            } else {
                o0[dx] = g0[0]*w1[dx][1] + g0[1]*w1[dx][2] + g0[2]*w1[dx][3]
                       + g1[0]*w2[dx][0] + g1[1]*w2[dx][1] + g1[2]*w2[dx][2]
                       + g1[3]*w2[dx][3] + g1[4]*A2;
                o1[dx] = g0[0]*w1[dx][2] + g0[1]*w1[dx][3] + g0[2]*A1
                       + g1[0]*w2[dx][1] + g1[1]*w2[dx][2] + g1[2]*w2[dx][3]
                       + g1[3]*A2 + g1[4]*Bb2;
                w1[dx][0] = w1[dx][2]; w1[dx][1] = w1[dx][3]; w1[dx][2] = A1; w1[dx][3] = Bb1;
                w2[dx][0] = w2[dx][2]; w2[dx][1] = w2[dx][3]; w2[dx][2] = A2; w2[dx][3] = Bb2;
            }
        }
        if (s >= 2) {
            const int r0 = i0 + 2 * (s - 2);
            *(float4*)(outp + (size_t)r0 * Ww + 4 * c) =
                make_float4(o0[0], o0[1], o0[2], o0[3]);
            *(float4*)(outp + (size_t)(r0 + 1) * Ww + 4 * c) =
                make_float4(o1[0], o1[1], o1[2], o1[3]);
        }
    };

    // Prologue: fill buf[0] with stage 0; SA <- stage 1.
    loadStage(0, SA);
    writeStage(0, SA);
    loadStage(1, SA);

    // Main loop, unrolled x2 for A/B register rotation (static indices only).
    for (int sb = 0; sb < NST; sb += 2) {
        loadStage(sb + 2, SB);        // issue loads 2 stages ahead
        compute(sb);
        writeStage(sb + 1, SA);       // SA's loads landed ~1 compute ago
        loadStage(sb + 3, SA);
        compute(sb + 1);
        if (sb + 2 < NST) writeStage(sb + 2, SB);
    }
}

extern "C" void kernel_launch(void* const* d_in, const int* in_sizes, int n_in,
                              void* d_out, int out_size, void* d_ws, size_t ws_size,
                              hipStream_t stream) {
    const float* Yl  = (const float*)d_in[0];
    const float* Yhr = (const float*)d_in[1];
    const float* Yhi = (const float*)d_in[2];
    const float* g0o = (const float*)d_in[3];
    const float* g1o = (const float*)d_in[4];
    float* outp = (float*)d_out;
    dim3 grid(256, Hh / TH);   // 256 planes x 8 row tiles, 1 wave per block
    dim3 block(64);
    hipLaunchKernelGGL(dtcwt_inv, grid, block, 0, stream,
                       Yl, Yhr, Yhi, g0o, g1o, outp);
}